// Round 10
// baseline (412.658 us; speedup 1.0000x reference)
//
#include <hip/hip_runtime.h>
#include <hip/hip_bf16.h>

#define HC 128
#define NHEAD 4
#define NEG 0.2f

typedef unsigned int uint32;
typedef __attribute__((ext_vector_type(8))) short short8v;   // 8 bf16 = 4 VGPR
typedef __attribute__((ext_vector_type(4))) float f32x4;

__device__ __forceinline__ float leaky(float v) { return v > 0.f ? v : NEG * v; }
__device__ __forceinline__ int clampi(int v, int lo, int hi) { return v < lo ? lo : (v > hi ? hi : v); }

__device__ __forceinline__ uint32 pack_bf16(float lo, float hi) {
  uint32 a = __float_as_uint(lo);
  uint32 b = __float_as_uint(hi);
  a = (a + 0x7FFFu + ((a >> 16) & 1u)) >> 16;
  b = (b + 0x7FFFu + ((b >> 16) & 1u)) & 0xFFFF0000u;
  return a | b;
}
__device__ __forceinline__ unsigned short bf16_1(float v) {
  uint32 a = __float_as_uint(v);
  return (unsigned short)((a + 0x7FFFu + ((a >> 16) & 1u)) >> 16);
}
__device__ __forceinline__ float2 unpack_bf16(uint32 u) {
  return make_float2(__uint_as_float(u << 16), __uint_as_float(u & 0xFFFF0000u));
}
__device__ __forceinline__ short8v as_s8(uint4 u) {
  union { uint4 a; short8v b; } c; c.a = u; return c.b;
}

// ---------------- utility ----------------
__global__ __launch_bounds__(256) void zero_kernel(int* __restrict__ p, int n) {
  int i = blockIdx.x * 256 + threadIdx.x;
  int stride = gridDim.x * 256;
  for (; i < n; i += stride) p[i] = 0;
}

// ---------------- CSR build ----------------
__global__ __launch_bounds__(256) void hist_kernel(const int* __restrict__ dst, int* __restrict__ cnt, int E, int n) {
  int e = blockIdx.x * 256 + threadIdx.x;
  if (e < E) {
    int d = clampi(dst[e], 0, n - 1);
    atomicAdd(&cnt[d], 1);
  }
}

__global__ __launch_bounds__(256) void scan_pass1(const int* __restrict__ cnt, int* __restrict__ blocksum, int n) {
  __shared__ int red[256];
  int t = threadIdx.x;
  int i = blockIdx.x * 256 + t;
  red[t] = i < n ? cnt[i] : 0;
  __syncthreads();
  for (int off = 128; off >= 1; off >>= 1) {
    if (t < off) red[t] += red[t + off];
    __syncthreads();
  }
  if (t == 0) blocksum[blockIdx.x] = red[0];
}

__global__ __launch_bounds__(256) void scan_pass2(const int* __restrict__ blocksum, int* __restrict__ blockpre,
                                                  int* __restrict__ row_start, int NB, int n) {
  __shared__ int part[256];
  int t = threadIdx.x;
  int chunk = (NB + 255) >> 8;
  int lo = t * chunk; if (lo > NB) lo = NB;
  int hi = lo + chunk; if (hi > NB) hi = NB;
  int s = 0;
  for (int i = lo; i < hi; ++i) s += blocksum[i];
  part[t] = s;
  __syncthreads();
  for (int off = 1; off < 256; off <<= 1) {
    int v = (t >= off) ? part[t - off] : 0;
    __syncthreads();
    part[t] += v;
    __syncthreads();
  }
  int run = part[t] - s;
  for (int i = lo; i < hi; ++i) {
    blockpre[i] = run;
    run += blocksum[i];
  }
  if (t == 255) row_start[n] = part[255];
}

__global__ __launch_bounds__(256) void scan_pass3(const int* __restrict__ cnt, const int* __restrict__ blockpre,
                                                  int* __restrict__ row_start, int* __restrict__ cursor, int n) {
  __shared__ int part[256];
  int t = threadIdx.x;
  int i = blockIdx.x * 256 + t;
  int c = i < n ? cnt[i] : 0;
  part[t] = c;
  __syncthreads();
  for (int off = 1; off < 256; off <<= 1) {
    int v = (t >= off) ? part[t - off] : 0;
    __syncthreads();
    part[t] += v;
    __syncthreads();
  }
  int excl = part[t] - c;
  if (i < n) {
    int b = blockpre[blockIdx.x] + excl;
    row_start[i] = b;
    cursor[i] = b;
  }
}

__global__ __launch_bounds__(256) void scatter_kernel(const int* __restrict__ src, const int* __restrict__ dst,
                                                      int* __restrict__ cursor, int* __restrict__ csr, int E, int n) {
  int e = blockIdx.x * 256 + threadIdx.x;
  if (e < E) {
    int d = clampi(dst[e], 0, n - 1);
    int s = clampi(src[e], 0, n - 1);
    int p = atomicAdd(&cursor[d], 1);
    if (p >= 0 && p < E) csr[p] = s;
  }
}

// ---------------- prep: W [128x128 fp32 row-major, 3 layers] -> Wt bf16 [n][k] ----
__global__ __launch_bounds__(256) void wprep(const float* __restrict__ W0, const float* __restrict__ W1,
                                             const float* __restrict__ W2, unsigned short* __restrict__ wt) {
  int g = blockIdx.x * 256 + threadIdx.x;
  if (g >= 3 * 16384) return;
  int l = g >> 14;
  int r = g & 16383;          // r = k*128 + n  (coalesced read)
  int k = r >> 7, nc = r & 127;
  const float* W = l == 0 ? W0 : (l == 1 ? W1 : W2);
  wt[(size_t)l * 16384 + nc * 128 + k] = bf16_1(W[r]);
}

// ---------------- prep: x fp32 [N][128] -> packed bf16 [N][64] ----------------
__global__ __launch_bounds__(256) void xprep(const float* __restrict__ x, uint32* __restrict__ X16, long long n64) {
  long long i = (long long)blockIdx.x * 256 + threadIdx.x;
  if (i >= n64) return;
  float2 v = *(const float2*)&x[i * 2];
  X16[i] = pack_bf16(v.x, v.y);
}

// ---------------- MFMA GEMM: H = X @ W + attention-coefficient epilogue ----------
__global__ __launch_bounds__(256) void gemm_mfma(const uint32* __restrict__ X16, const unsigned short* __restrict__ Wt,
                                                 const float* __restrict__ a_src, const float* __restrict__ a_dst,
                                                 uint32* __restrict__ H16, float* __restrict__ As,
                                                 float* __restrict__ Ad, int n) {
  int t = threadIdx.x;
  int wave = t >> 6, lane = t & 63;
  int l15 = lane & 15, lg = lane >> 4;
  int row0 = blockIdx.x * 64 + wave * 16;
  int arow = row0 + l15;
  if (arow >= n) arow = n - 1;
  const uint4* xr = (const uint4*)(X16 + (size_t)arow * 64);
  uint4 a[4];
#pragma unroll
  for (int kc = 0; kc < 4; ++kc) a[kc] = xr[kc * 4 + lg];
  f32x4 acc[8];
#pragma unroll
  for (int nb = 0; nb < 8; ++nb) acc[nb] = (f32x4){0.f, 0.f, 0.f, 0.f};
#pragma unroll
  for (int kc = 0; kc < 4; ++kc) {
    uint4 b[8];
#pragma unroll
    for (int nb = 0; nb < 8; ++nb) {
      int ncol = nb * 16 + l15;
      b[nb] = *(const uint4*)(Wt + (size_t)ncol * 128 + kc * 32 + lg * 8);
    }
#pragma unroll
    for (int nb = 0; nb < 8; ++nb)
      acc[nb] = __builtin_amdgcn_mfma_f32_16x16x32_bf16(as_s8(a[kc]), as_s8(b[nb]), acc[nb], 0, 0, 0);
  }
  float asv[8], adv[8];
#pragma unroll
  for (int nb = 0; nb < 8; ++nb) {
    asv[nb] = a_src[nb * 16 + l15];
    adv[nb] = a_dst[nb * 16 + l15];
  }
#pragma unroll
  for (int r = 0; r < 4; ++r) {
    int gr = row0 + lg * 4 + r;
    bool ok = gr < n;
    float psh[4], pdh[4];
#pragma unroll
    for (int h = 0; h < 4; ++h) {
      float ps = acc[2 * h][r] * asv[2 * h] + acc[2 * h + 1][r] * asv[2 * h + 1];
      float pd = acc[2 * h][r] * adv[2 * h] + acc[2 * h + 1][r] * adv[2 * h + 1];
#pragma unroll
      for (int off = 1; off < 16; off <<= 1) {
        ps += __shfl_xor(ps, off);
        pd += __shfl_xor(pd, off);
      }
      psh[h] = ps;
      pdh[h] = pd;
    }
    if (ok && l15 == 0) {
#pragma unroll
      for (int h = 0; h < 4; ++h) {
        As[gr * 4 + h] = psh[h];
        Ad[gr * 4 + h] = pdh[h];
      }
    }
#pragma unroll
    for (int nb = 0; nb < 8; ++nb) {
      float mine = acc[nb][r];
      float other = __shfl_xor(mine, 1);
      if (ok && (lane & 1) == 0) H16[(size_t)gr * 64 + nb * 8 + (l15 >> 1)] = pack_bf16(mine, other);
    }
  }
}

// ---------------- fused softmax + aggregation (split-pair, wave per node) --------
// Half-waves process DIFFERENT edges: lane covers 4 channels (uint2 = 8B) of
// edge (u0 + 2i + half). Per 2 edges: 1 idx-shfl + 1 alpha-shfl + 1 load
// (per-lane shfl source). 8 loads in flight = 16 edges. Denominator/acc
// combined across halves once at the end via shfl_xor(32); self term added
// post-combine on half 0 only.
template <bool OUTFP32>
__global__ __launch_bounds__(256) void agg_kernel(const uint32* __restrict__ H16, const float* __restrict__ As,
                                                  const float* __restrict__ Ad, const int* __restrict__ row_start,
                                                  const int* __restrict__ csr, const float* __restrict__ bias,
                                                  void* __restrict__ outv, int n) {
  int wid = (blockIdx.x * 256 + threadIdx.x) >> 6;
  int lane = threadIdx.x & 63;
  if (wid >= n) return;
  int base = row_start[wid];
  int deg = row_start[wid + 1] - base;
  if (deg < 0) deg = 0;
  int half = lane >> 5;
  int c16 = lane & 31;          // channels 4*c16 .. 4*c16+3
  int hsel = c16 >> 3;          // head of those channels
  int slot16 = lane & 15;       // pm-compute slot
  int hgrp = lane >> 4;         // pm-compute head
  float ad_pm = Ad[wid * 4 + hgrp];
  float ad_my = Ad[wid * 4 + hsel];
  float pself = __expf(leaky(As[wid * 4 + hsel] + ad_my));
  float denp = 0.f;
  float acc0 = 0.f, acc1 = 0.f, acc2 = 0.f, acc3 = 0.f;
  for (int chunk = 0; chunk < deg; chunk += 64) {
    int j = chunk + lane;
    int smine = (j < deg) ? csr[base + j] : 0;
    int cnt_ = deg - chunk; if (cnt_ > 64) cnt_ = 64;
    // pm[k]: alpha for edge slot (lane&15)+16k, head (lane>>4)
    float pm[4];
#pragma unroll
    for (int k = 0; k < 4; ++k) {
      int slot = k * 16 + slot16;
      int sk = __shfl(smine, slot);
      float e = As[sk * 4 + hgrp];
      pm[k] = (slot < cnt_) ? __expf(leaky(e + ad_pm)) : 0.f;
    }
#pragma unroll
    for (int k = 0; k < 4; ++k) {
      int u0 = k * 16;
      if (u0 >= cnt_) break;  // wave-uniform
      int ss[8];
      uint2 h2[8];
#pragma unroll
      for (int i = 0; i < 8; ++i) ss[i] = __shfl(smine, u0 + 2 * i + half);
#pragma unroll
      for (int i = 0; i < 8; ++i) h2[i] = *(const uint2*)(H16 + (size_t)((uint32)ss[i]) * 64 + c16 * 2);
      if (u0 + 16 <= cnt_) {
#pragma unroll
        for (int i = 0; i < 8; ++i) {
          float aw = __shfl(pm[k], 16 * hsel + 2 * i + half);
          denp += aw;
          float2 ab = unpack_bf16(h2[i].x), cd = unpack_bf16(h2[i].y);
          acc0 += aw * ab.x; acc1 += aw * ab.y;
          acc2 += aw * cd.x; acc3 += aw * cd.y;
        }
      } else {
#pragma unroll
        for (int i = 0; i < 8; ++i) {
          int u = u0 + 2 * i + half;
          float av = __shfl(pm[k], 16 * hsel + 2 * i + half);
          float aw = (u < cnt_) ? av : 0.f;
          denp += aw;
          float2 ab = unpack_bf16(h2[i].x), cd = unpack_bf16(h2[i].y);
          acc0 += aw * ab.x; acc1 += aw * ab.y;
          acc2 += aw * cd.x; acc3 += aw * cd.y;
        }
      }
    }
  }
  // combine halves
  denp += __shfl_xor(denp, 32);
  acc0 += __shfl_xor(acc0, 32);
  acc1 += __shfl_xor(acc1, 32);
  acc2 += __shfl_xor(acc2, 32);
  acc3 += __shfl_xor(acc3, 32);
  if (half == 0) {
    uint2 hs = *(const uint2*)(H16 + (size_t)wid * 64 + c16 * 2);
    float2 ab = unpack_bf16(hs.x), cd = unpack_bf16(hs.y);
    acc0 += pself * ab.x; acc1 += pself * ab.y;
    acc2 += pself * cd.x; acc3 += pself * cd.y;
    float inv = 1.f / (denp + pself);
    float4 bv = *(const float4*)&bias[c16 * 4];
    float r0 = fmaxf(acc0 * inv + bv.x, 0.f);
    float r1 = fmaxf(acc1 * inv + bv.y, 0.f);
    float r2 = fmaxf(acc2 * inv + bv.z, 0.f);
    float r3 = fmaxf(acc3 * inv + bv.w, 0.f);
    if constexpr (OUTFP32) {
      *(float4*)&((float*)outv)[(size_t)wid * 128 + c16 * 4] = make_float4(r0, r1, r2, r3);
    } else {
      uint2 o;
      o.x = pack_bf16(r0, r1);
      o.y = pack_bf16(r2, r3);
      *(uint2*)&((uint32*)outv)[(size_t)wid * 64 + c16 * 2] = o;
    }
  }
}

// ---------------- pooling ----------------
__global__ __launch_bounds__(128) void pool_kernel(const float* __restrict__ X, const int* __restrict__ batch,
                                                   float* __restrict__ pooled, int n, int G) {
  int c = threadIdx.x;
  int n0 = blockIdx.x * 64;
  if (n0 >= n) return;
  int end = n0 + 64 < n ? n0 + 64 : n;
  int curg = clampi(batch[n0], 0, G - 1);
  float acc = 0.f;
  for (int i = n0; i < end; ++i) {
    int g = clampi(batch[i], 0, G - 1);
    if (g != curg) {
      atomicAdd(&pooled[curg * 128 + c], acc);
      acc = 0.f;
      curg = g;
    }
    acc += X[(size_t)i * 128 + c];
  }
  atomicAdd(&pooled[curg * 128 + c], acc);
}

__global__ __launch_bounds__(64) void logits_kernel(const float* __restrict__ pooled, const float* __restrict__ Wh,
                                                    const float* __restrict__ bh, float* __restrict__ out) {
  int g = blockIdx.x, lane = threadIdx.x;
  float p0 = pooled[g * 128 + lane];
  float p1 = pooled[g * 128 + lane + 64];
  for (int o = 0; o < 10; ++o) {
    float v = p0 * Wh[lane * 10 + o] + p1 * Wh[(lane + 64) * 10 + o];
#pragma unroll
    for (int off = 32; off >= 1; off >>= 1) v += __shfl_xor(v, off);
    if (lane == 0) out[g * 10 + o] = v + bh[o];
  }
}

extern "C" void kernel_launch(void* const* d_in, const int* in_sizes, int n_in,
                              void* d_out, int out_size, void* d_ws, size_t ws_size,
                              hipStream_t stream) {
  const float *x, *Wl[3], *asr[3], *adr[3], *bias[3], *Wh, *bh;
  const int *edge_index, *batch;
  long long E_ll;
  if (n_in >= 17) {
    x = (const float*)d_in[0];
    for (int l = 0; l < 3; ++l) {
      Wl[l] = (const float*)d_in[1 + l];
      asr[l] = (const float*)d_in[4 + l];
      adr[l] = (const float*)d_in[7 + l];
      bias[l] = (const float*)d_in[10 + l];
    }
    Wh = (const float*)d_in[13];
    bh = (const float*)d_in[14];
    edge_index = (const int*)d_in[15];
    batch = (const int*)d_in[16];
    E_ll = (long long)in_sizes[15] / 2;
  } else if (n_in >= 9) {
    x = (const float*)d_in[0];
    const float* Wc = (const float*)d_in[1];
    const float* ac = (const float*)d_in[2];
    const float* dc = (const float*)d_in[3];
    const float* bc = (const float*)d_in[4];
    for (int l = 0; l < 3; ++l) {
      Wl[l] = Wc + (size_t)l * HC * HC;
      asr[l] = ac + (size_t)l * HC;
      adr[l] = dc + (size_t)l * HC;
      bias[l] = bc + (size_t)l * HC;
    }
    Wh = (const float*)d_in[5];
    bh = (const float*)d_in[6];
    edge_index = (const int*)d_in[7];
    batch = (const int*)d_in[8];
    E_ll = (long long)in_sizes[7] / 2;
  } else {
    zero_kernel<<<(out_size + 255) / 256, 256, 0, stream>>>((int*)d_out, out_size);
    return;
  }
  int N = in_sizes[0] / HC;
  int G = out_size / 10;
  if (N <= 0 || G <= 0 || E_ll <= 0 || E_ll > (1LL << 30)) {
    zero_kernel<<<(out_size + 255) / 256, 256, 0, stream>>>((int*)d_out, out_size);
    return;
  }
  int E = (int)E_ll;
  int NB = (N + 255) / 256;

  char* w = (char*)d_ws;
  size_t off = 0;
  auto take = [&](size_t bytes) -> char* {
    char* p = w + off;
    off = (off + bytes + 511) & ~(size_t)511;
    return p;
  };
  uint32* H16 = (uint32*)take((size_t)N * 64 * 4);
  uint32* X16 = (uint32*)take((size_t)N * 64 * 4);
  float* bufQ = (float*)take((size_t)N * HC * 4);   // layer-2 fp32 output
  uint32* Xa = (uint32*)bufQ;                        // aliased: bf16 x (used only before bufQ)
  float* As = (float*)take((size_t)N * NHEAD * 4);
  float* Ad = (float*)take((size_t)N * NHEAD * 4);
  int* cnt = (int*)take((size_t)N * 4);
  int* row_start = (int*)take((size_t)(N + 1) * 4);
  int* cursor = (int*)take((size_t)N * 4);
  int* csr = (int*)take((size_t)E * 4);
  int* blocksum = (int*)take((size_t)NB * 4);
  int* blockpre = (int*)take((size_t)NB * 4);
  float* pooled = (float*)take((size_t)G * HC * 4);
  unsigned short* wt16 = (unsigned short*)take((size_t)3 * 16384 * 2);

  if (off > ws_size) {
    zero_kernel<<<(out_size + 255) / 256, 256, 0, stream>>>((int*)d_out, out_size);
    return;
  }

  const int* esrc = edge_index;
  const int* edst = edge_index + E;

  zero_kernel<<<(N + 255) / 256, 256, 0, stream>>>(cnt, N);
  hist_kernel<<<(E + 255) / 256, 256, 0, stream>>>(edst, cnt, E, N);
  scan_pass1<<<NB, 256, 0, stream>>>(cnt, blocksum, N);
  scan_pass2<<<1, 256, 0, stream>>>(blocksum, blockpre, row_start, NB, N);
  scan_pass3<<<NB, 256, 0, stream>>>(cnt, blockpre, row_start, cursor, N);
  scatter_kernel<<<(E + 255) / 256, 256, 0, stream>>>(esrc, edst, cursor, csr, E, N);

  wprep<<<(3 * 16384 + 255) / 256, 256, 0, stream>>>(Wl[0], Wl[1], Wl[2], wt16);
  long long n64 = (long long)N * 64;
  xprep<<<(int)((n64 + 255) / 256), 256, 0, stream>>>(x, Xa, n64);

  int gemm_grid = (N + 63) / 64;
  int agg_grid = (N + 3) / 4;

  // layer 0
  gemm_mfma<<<gemm_grid, 256, 0, stream>>>(Xa, wt16, asr[0], adr[0], H16, As, Ad, N);
  agg_kernel<false><<<agg_grid, 256, 0, stream>>>(H16, As, Ad, row_start, csr, bias[0], X16, N);
  // layer 1
  gemm_mfma<<<gemm_grid, 256, 0, stream>>>(X16, wt16 + 16384, asr[1], adr[1], H16, As, Ad, N);
  agg_kernel<false><<<agg_grid, 256, 0, stream>>>(H16, As, Ad, row_start, csr, bias[1], X16, N);
  // layer 2 (agg -> fp32 bufQ; Xa no longer needed)
  gemm_mfma<<<gemm_grid, 256, 0, stream>>>(X16, wt16 + 2 * 16384, asr[2], adr[2], H16, As, Ad, N);
  agg_kernel<true><<<agg_grid, 256, 0, stream>>>(H16, As, Ad, row_start, csr, bias[2], bufQ, N);

  zero_kernel<<<(G * HC + 255) / 256, 256, 0, stream>>>((int*)pooled, G * HC);
  pool_kernel<<<(N + 63) / 64, 128, 0, stream>>>(bufQ, batch, pooled, N, G);
  logits_kernel<<<G, 64, 0, stream>>>(pooled, Wh, bh, (float*)d_out);
}

// Round 11
// 381.519 us; speedup vs baseline: 1.0816x; 1.0816x over previous
//
#include <hip/hip_runtime.h>
#include <hip/hip_bf16.h>

#define HC 128
#define NHEAD 4
#define NEG 0.2f

typedef unsigned int uint32;
typedef __attribute__((ext_vector_type(8))) short short8v;   // 8 bf16 = 4 VGPR
typedef __attribute__((ext_vector_type(4))) float f32x4;

__device__ __forceinline__ float leaky(float v) { return v > 0.f ? v : NEG * v; }
__device__ __forceinline__ int clampi(int v, int lo, int hi) { return v < lo ? lo : (v > hi ? hi : v); }

__device__ __forceinline__ uint32 pack_bf16(float lo, float hi) {
  uint32 a = __float_as_uint(lo);
  uint32 b = __float_as_uint(hi);
  a = (a + 0x7FFFu + ((a >> 16) & 1u)) >> 16;
  b = (b + 0x7FFFu + ((b >> 16) & 1u)) & 0xFFFF0000u;
  return a | b;
}
__device__ __forceinline__ unsigned short bf16_1(float v) {
  uint32 a = __float_as_uint(v);
  return (unsigned short)((a + 0x7FFFu + ((a >> 16) & 1u)) >> 16);
}
__device__ __forceinline__ float2 unpack_bf16(uint32 u) {
  return make_float2(__uint_as_float(u << 16), __uint_as_float(u & 0xFFFF0000u));
}
__device__ __forceinline__ short8v as_s8(uint4 u) {
  union { uint4 a; short8v b; } c; c.a = u; return c.b;
}

// ---------------- utility ----------------
__global__ __launch_bounds__(256) void zero_kernel(int* __restrict__ p, int n) {
  int i = blockIdx.x * 256 + threadIdx.x;
  int stride = gridDim.x * 256;
  for (; i < n; i += stride) p[i] = 0;
}

// ---------------- CSR build ----------------
__global__ __launch_bounds__(256) void hist_kernel(const int* __restrict__ dst, int* __restrict__ cnt, int E, int n) {
  int e = blockIdx.x * 256 + threadIdx.x;
  if (e < E) {
    int d = clampi(dst[e], 0, n - 1);
    atomicAdd(&cnt[d], 1);
  }
}

__global__ __launch_bounds__(256) void scan_pass1(const int* __restrict__ cnt, int* __restrict__ blocksum, int n) {
  __shared__ int red[256];
  int t = threadIdx.x;
  int i = blockIdx.x * 256 + t;
  red[t] = i < n ? cnt[i] : 0;
  __syncthreads();
  for (int off = 128; off >= 1; off >>= 1) {
    if (t < off) red[t] += red[t + off];
    __syncthreads();
  }
  if (t == 0) blocksum[blockIdx.x] = red[0];
}

__global__ __launch_bounds__(256) void scan_pass2(const int* __restrict__ blocksum, int* __restrict__ blockpre,
                                                  int* __restrict__ row_start, int NB, int n) {
  __shared__ int part[256];
  int t = threadIdx.x;
  int chunk = (NB + 255) >> 8;
  int lo = t * chunk; if (lo > NB) lo = NB;
  int hi = lo + chunk; if (hi > NB) hi = NB;
  int s = 0;
  for (int i = lo; i < hi; ++i) s += blocksum[i];
  part[t] = s;
  __syncthreads();
  for (int off = 1; off < 256; off <<= 1) {
    int v = (t >= off) ? part[t - off] : 0;
    __syncthreads();
    part[t] += v;
    __syncthreads();
  }
  int run = part[t] - s;
  for (int i = lo; i < hi; ++i) {
    blockpre[i] = run;
    run += blocksum[i];
  }
  if (t == 255) row_start[n] = part[255];
}

__global__ __launch_bounds__(256) void scan_pass3(const int* __restrict__ cnt, const int* __restrict__ blockpre,
                                                  int* __restrict__ row_start, int* __restrict__ cursor, int n) {
  __shared__ int part[256];
  int t = threadIdx.x;
  int i = blockIdx.x * 256 + t;
  int c = i < n ? cnt[i] : 0;
  part[t] = c;
  __syncthreads();
  for (int off = 1; off < 256; off <<= 1) {
    int v = (t >= off) ? part[t - off] : 0;
    __syncthreads();
    part[t] += v;
    __syncthreads();
  }
  int excl = part[t] - c;
  if (i < n) {
    int b = blockpre[blockIdx.x] + excl;
    row_start[i] = b;
    cursor[i] = b;
  }
}

__global__ __launch_bounds__(256) void scatter_kernel(const int* __restrict__ src, const int* __restrict__ dst,
                                                      int* __restrict__ cursor, int* __restrict__ csr, int E, int n) {
  int e = blockIdx.x * 256 + threadIdx.x;
  if (e < E) {
    int d = clampi(dst[e], 0, n - 1);
    int s = clampi(src[e], 0, n - 1);
    int p = atomicAdd(&cursor[d], 1);
    if (p >= 0 && p < E) csr[p] = s;
  }
}

// ---------------- prep: W [128x128 fp32 row-major, 3 layers] -> Wt bf16 [n][k] ----
__global__ __launch_bounds__(256) void wprep(const float* __restrict__ W0, const float* __restrict__ W1,
                                             const float* __restrict__ W2, unsigned short* __restrict__ wt) {
  int g = blockIdx.x * 256 + threadIdx.x;
  if (g >= 3 * 16384) return;
  int l = g >> 14;
  int r = g & 16383;          // r = k*128 + n  (coalesced read)
  int k = r >> 7, nc = r & 127;
  const float* W = l == 0 ? W0 : (l == 1 ? W1 : W2);
  wt[(size_t)l * 16384 + nc * 128 + k] = bf16_1(W[r]);
}

// ---------------- prep: x fp32 [N][128] -> packed bf16 [N][64] ----------------
__global__ __launch_bounds__(256) void xprep(const float* __restrict__ x, uint32* __restrict__ X16, long long n64) {
  long long i = (long long)blockIdx.x * 256 + threadIdx.x;
  if (i >= n64) return;
  float2 v = *(const float2*)&x[i * 2];
  X16[i] = pack_bf16(v.x, v.y);
}

// ---------------- MFMA GEMM: H = X @ W (pure; no attention epilogue) -------------
// bf16 in (packed X16 rows), Wt bf16 [n][k] k-contiguous. Wave owns 16 rows x
// 128 cols = 8 nb-tiles x 4 k-chunks = 32 mfma_f32_16x16x32_bf16.
// D layout (verified m89): col = lane&15, row = 4*(lane>>4)+reg.
__global__ __launch_bounds__(256) void gemm_mfma(const uint32* __restrict__ X16, const unsigned short* __restrict__ Wt,
                                                 uint32* __restrict__ H16, int n) {
  int t = threadIdx.x;
  int wave = t >> 6, lane = t & 63;
  int l15 = lane & 15, lg = lane >> 4;
  int row0 = blockIdx.x * 64 + wave * 16;
  int arow = row0 + l15;
  if (arow >= n) arow = n - 1;
  const uint4* xr = (const uint4*)(X16 + (size_t)arow * 64);
  uint4 a[4];
#pragma unroll
  for (int kc = 0; kc < 4; ++kc) a[kc] = xr[kc * 4 + lg];
  f32x4 acc[8];
#pragma unroll
  for (int nb = 0; nb < 8; ++nb) acc[nb] = (f32x4){0.f, 0.f, 0.f, 0.f};
#pragma unroll
  for (int kc = 0; kc < 4; ++kc) {
    uint4 b[8];
#pragma unroll
    for (int nb = 0; nb < 8; ++nb) {
      int ncol = nb * 16 + l15;
      b[nb] = *(const uint4*)(Wt + (size_t)ncol * 128 + kc * 32 + lg * 8);
    }
#pragma unroll
    for (int nb = 0; nb < 8; ++nb)
      acc[nb] = __builtin_amdgcn_mfma_f32_16x16x32_bf16(as_s8(a[kc]), as_s8(b[nb]), acc[nb], 0, 0, 0);
  }
#pragma unroll
  for (int r = 0; r < 4; ++r) {
    int gr = row0 + lg * 4 + r;
    bool ok = gr < n;
#pragma unroll
    for (int nb = 0; nb < 8; ++nb) {
      float mine = acc[nb][r];
      float other = __shfl_xor(mine, 1);
      if (ok && (lane & 1) == 0) H16[(size_t)gr * 64 + nb * 8 + (l15 >> 1)] = pack_bf16(mine, other);
    }
  }
}

// ---------------- attention coefficients from H16 (wave = 2 nodes) ----------------
// Half-wave (32 lanes) per node; lane covers channels [4*c4, 4*c4+4) (uint2).
// head = c4>>3; reduce over the 8 lanes of that head via 3-round butterfly.
__global__ __launch_bounds__(256) void alpha16_kernel(const uint32* __restrict__ H16, const float* __restrict__ a_src,
                                                      const float* __restrict__ a_dst, float* __restrict__ As,
                                                      float* __restrict__ Ad, int n) {
  int wv = (blockIdx.x * 256 + threadIdx.x) >> 6;
  int lane = threadIdx.x & 63;
  int half = lane >> 5, c4 = lane & 31;
  int node = wv * 2 + half;
  if (node >= n) return;
  uint2 hu = *(const uint2*)(H16 + (size_t)node * 64 + c4 * 2);
  float2 ab = unpack_bf16(hu.x), cd = unpack_bf16(hu.y);
  float4 sv = *(const float4*)&a_src[c4 * 4];
  float4 dv = *(const float4*)&a_dst[c4 * 4];
  float ps = ab.x * sv.x + ab.y * sv.y + cd.x * sv.z + cd.y * sv.w;
  float pd = ab.x * dv.x + ab.y * dv.y + cd.x * dv.z + cd.y * dv.w;
#pragma unroll
  for (int off = 1; off < 8; off <<= 1) {
    ps += __shfl_xor(ps, off);
    pd += __shfl_xor(pd, off);
  }
  if ((lane & 7) == 0) {
    As[node * 4 + (c4 >> 3)] = ps;
    Ad[node * 4 + (c4 >> 3)] = pd;
  }
}

// ---------------- fused softmax + aggregation (wave per node, 8-deep MLP) --------
template <bool OUTFP32>
__global__ __launch_bounds__(256) void agg_kernel(const uint32* __restrict__ H16, const float* __restrict__ As,
                                                  const float* __restrict__ Ad, const int* __restrict__ row_start,
                                                  const int* __restrict__ csr, const float* __restrict__ bias,
                                                  void* __restrict__ outv, int n) {
  int wid = (blockIdx.x * 256 + threadIdx.x) >> 6;
  int lane = threadIdx.x & 63;
  if (wid >= n) return;
  int base = row_start[wid];
  int deg = row_start[wid + 1] - base;
  if (deg < 0) deg = 0;
  int hsel = lane >> 4;
  float adsel = Ad[wid * 4 + hsel];
  float pself = __expf(leaky(As[wid * 4 + hsel] + adsel));
  float2 hv = unpack_bf16(H16[(size_t)wid * 64 + lane]);
  float den = pself;
  float acc0 = pself * hv.x, acc1 = pself * hv.y;
  for (int chunk = 0; chunk < deg; chunk += 64) {
    int j = chunk + lane;
    int smine = (j < deg) ? clampi(csr[base + j], 0, n - 1) : 0;
    int cnt_ = deg - chunk; if (cnt_ > 64) cnt_ = 64;
    float pm[4];
#pragma unroll
    for (int k = 0; k < 4; ++k) {
      int slot = k * 16 + (lane & 15);
      int sk = __shfl(smine, slot);
      float e = As[sk * 4 + hsel];
      pm[k] = (slot < cnt_) ? __expf(leaky(e + adsel)) : 0.f;
    }
#pragma unroll
    for (int k = 0; k < 4; ++k) {
      if (k * 16 >= cnt_) break;
#pragma unroll
      for (int b = 0; b < 2; ++b) {
        int u0 = k * 16 + b * 8;
        if (u0 >= cnt_) break;
        int ss[8];
        float aw[8];
        float2 h2[8];
#pragma unroll
        for (int i = 0; i < 8; ++i) {
          int u = u0 + i;
          int sv = __shfl(smine, u);
          float av = __shfl(pm[k], (lane & 48) + (u & 15));
          ss[i] = (u < cnt_) ? sv : 0;
          aw[i] = (u < cnt_) ? av : 0.f;
        }
#pragma unroll
        for (int i = 0; i < 8; ++i) h2[i] = unpack_bf16(H16[(size_t)((uint32)ss[i] * 64 + lane)]);
#pragma unroll
        for (int i = 0; i < 8; ++i) {
          den += aw[i];
          acc0 += aw[i] * h2[i].x;
          acc1 += aw[i] * h2[i].y;
        }
      }
    }
  }
  float inv = 1.f / den;
  float2 bv = *(const float2*)&bias[2 * lane];
  float r0v = fmaxf(acc0 * inv + bv.x, 0.f);
  float r1v = fmaxf(acc1 * inv + bv.y, 0.f);
  if constexpr (OUTFP32) {
    ((float2*)outv)[(size_t)wid * 64 + lane] = make_float2(r0v, r1v);
  } else {
    ((uint32*)outv)[(size_t)wid * 64 + lane] = pack_bf16(r0v, r1v);
  }
}

// ---------------- pooling ----------------
__global__ __launch_bounds__(128) void pool_kernel(const float* __restrict__ X, const int* __restrict__ batch,
                                                   float* __restrict__ pooled, int n, int G) {
  int c = threadIdx.x;
  int n0 = blockIdx.x * 64;
  if (n0 >= n) return;
  int end = n0 + 64 < n ? n0 + 64 : n;
  int curg = clampi(batch[n0], 0, G - 1);
  float acc = 0.f;
  for (int i = n0; i < end; ++i) {
    int g = clampi(batch[i], 0, G - 1);
    if (g != curg) {
      atomicAdd(&pooled[curg * 128 + c], acc);
      acc = 0.f;
      curg = g;
    }
    acc += X[(size_t)i * 128 + c];
  }
  atomicAdd(&pooled[curg * 128 + c], acc);
}

__global__ __launch_bounds__(64) void logits_kernel(const float* __restrict__ pooled, const float* __restrict__ Wh,
                                                    const float* __restrict__ bh, float* __restrict__ out) {
  int g = blockIdx.x, lane = threadIdx.x;
  float p0 = pooled[g * 128 + lane];
  float p1 = pooled[g * 128 + lane + 64];
  for (int o = 0; o < 10; ++o) {
    float v = p0 * Wh[lane * 10 + o] + p1 * Wh[(lane + 64) * 10 + o];
#pragma unroll
    for (int off = 32; off >= 1; off >>= 1) v += __shfl_xor(v, off);
    if (lane == 0) out[g * 10 + o] = v + bh[o];
  }
}

extern "C" void kernel_launch(void* const* d_in, const int* in_sizes, int n_in,
                              void* d_out, int out_size, void* d_ws, size_t ws_size,
                              hipStream_t stream) {
  const float *x, *Wl[3], *asr[3], *adr[3], *bias[3], *Wh, *bh;
  const int *edge_index, *batch;
  long long E_ll;
  if (n_in >= 17) {
    x = (const float*)d_in[0];
    for (int l = 0; l < 3; ++l) {
      Wl[l] = (const float*)d_in[1 + l];
      asr[l] = (const float*)d_in[4 + l];
      adr[l] = (const float*)d_in[7 + l];
      bias[l] = (const float*)d_in[10 + l];
    }
    Wh = (const float*)d_in[13];
    bh = (const float*)d_in[14];
    edge_index = (const int*)d_in[15];
    batch = (const int*)d_in[16];
    E_ll = (long long)in_sizes[15] / 2;
  } else if (n_in >= 9) {
    x = (const float*)d_in[0];
    const float* Wc = (const float*)d_in[1];
    const float* ac = (const float*)d_in[2];
    const float* dc = (const float*)d_in[3];
    const float* bc = (const float*)d_in[4];
    for (int l = 0; l < 3; ++l) {
      Wl[l] = Wc + (size_t)l * HC * HC;
      asr[l] = ac + (size_t)l * HC;
      adr[l] = dc + (size_t)l * HC;
      bias[l] = bc + (size_t)l * HC;
    }
    Wh = (const float*)d_in[5];
    bh = (const float*)d_in[6];
    edge_index = (const int*)d_in[7];
    batch = (const int*)d_in[8];
    E_ll = (long long)in_sizes[7] / 2;
  } else {
    zero_kernel<<<(out_size + 255) / 256, 256, 0, stream>>>((int*)d_out, out_size);
    return;
  }
  int N = in_sizes[0] / HC;
  int G = out_size / 10;
  if (N <= 0 || G <= 0 || E_ll <= 0 || E_ll > (1LL << 30)) {
    zero_kernel<<<(out_size + 255) / 256, 256, 0, stream>>>((int*)d_out, out_size);
    return;
  }
  int E = (int)E_ll;
  int NB = (N + 255) / 256;

  char* w = (char*)d_ws;
  size_t off = 0;
  auto take = [&](size_t bytes) -> char* {
    char* p = w + off;
    off = (off + bytes + 511) & ~(size_t)511;
    return p;
  };
  uint32* H16 = (uint32*)take((size_t)N * 64 * 4);
  uint32* X16 = (uint32*)take((size_t)N * 64 * 4);
  float* bufQ = (float*)take((size_t)N * HC * 4);   // layer-2 fp32 output
  uint32* Xa = (uint32*)bufQ;                        // aliased: bf16 x (used only before bufQ)
  float* As = (float*)take((size_t)N * NHEAD * 4);
  float* Ad = (float*)take((size_t)N * NHEAD * 4);
  int* cnt = (int*)take((size_t)N * 4);
  int* row_start = (int*)take((size_t)(N + 1) * 4);
  int* cursor = (int*)take((size_t)N * 4);
  int* csr = (int*)take((size_t)E * 4);
  int* blocksum = (int*)take((size_t)NB * 4);
  int* blockpre = (int*)take((size_t)NB * 4);
  float* pooled = (float*)take((size_t)G * HC * 4);
  unsigned short* wt16 = (unsigned short*)take((size_t)3 * 16384 * 2);

  if (off > ws_size) {
    zero_kernel<<<(out_size + 255) / 256, 256, 0, stream>>>((int*)d_out, out_size);
    return;
  }

  const int* esrc = edge_index;
  const int* edst = edge_index + E;

  zero_kernel<<<(N + 255) / 256, 256, 0, stream>>>(cnt, N);
  hist_kernel<<<(E + 255) / 256, 256, 0, stream>>>(edst, cnt, E, N);
  scan_pass1<<<NB, 256, 0, stream>>>(cnt, blocksum, N);
  scan_pass2<<<1, 256, 0, stream>>>(blocksum, blockpre, row_start, NB, N);
  scan_pass3<<<NB, 256, 0, stream>>>(cnt, blockpre, row_start, cursor, N);
  scatter_kernel<<<(E + 255) / 256, 256, 0, stream>>>(esrc, edst, cursor, csr, E, N);

  wprep<<<(3 * 16384 + 255) / 256, 256, 0, stream>>>(Wl[0], Wl[1], Wl[2], wt16);
  long long n64 = (long long)N * 64;
  xprep<<<(int)((n64 + 255) / 256), 256, 0, stream>>>(x, Xa, n64);

  int gemm_grid = (N + 63) / 64;
  int agg_grid = (N + 3) / 4;
  int alpha_grid = (N + 7) / 8;

  // layer 0
  gemm_mfma<<<gemm_grid, 256, 0, stream>>>(Xa, wt16, H16, N);
  alpha16_kernel<<<alpha_grid, 256, 0, stream>>>(H16, asr[0], adr[0], As, Ad, N);
  agg_kernel<false><<<agg_grid, 256, 0, stream>>>(H16, As, Ad, row_start, csr, bias[0], X16, N);
  // layer 1
  gemm_mfma<<<gemm_grid, 256, 0, stream>>>(X16, wt16 + 16384, H16, N);
  alpha16_kernel<<<alpha_grid, 256, 0, stream>>>(H16, asr[1], adr[1], As, Ad, N);
  agg_kernel<false><<<agg_grid, 256, 0, stream>>>(H16, As, Ad, row_start, csr, bias[1], X16, N);
  // layer 2 (agg -> fp32 bufQ; Xa no longer needed)
  gemm_mfma<<<gemm_grid, 256, 0, stream>>>(X16, wt16 + 2 * 16384, H16, N);
  alpha16_kernel<<<alpha_grid, 256, 0, stream>>>(H16, asr[2], adr[2], As, Ad, N);
  agg_kernel<true><<<agg_grid, 256, 0, stream>>>(H16, As, Ad, row_start, csr, bias[2], bufQ, N);

  zero_kernel<<<(G * HC + 255) / 256, 256, 0, stream>>>((int*)pooled, G * HC);
  pool_kernel<<<(N + 63) / 64, 128, 0, stream>>>(bufQ, batch, pooled, N, G);
  logits_kernel<<<G, 64, 0, stream>>>(pooled, Wh, bh, (float*)d_out);
}

// Round 12
// 333.512 us; speedup vs baseline: 1.2373x; 1.1439x over previous
//
#include <hip/hip_runtime.h>
#include <hip/hip_bf16.h>

#define HC 128
#define NHEAD 4
#define NEG 0.2f

typedef unsigned int uint32;
typedef __attribute__((ext_vector_type(8))) short short8v;   // 8 bf16 = 4 VGPR
typedef __attribute__((ext_vector_type(4))) float f32x4;

__device__ __forceinline__ float leaky(float v) { return v > 0.f ? v : NEG * v; }
__device__ __forceinline__ int clampi(int v, int lo, int hi) { return v < lo ? lo : (v > hi ? hi : v); }

__device__ __forceinline__ uint32 pack_bf16(float lo, float hi) {
  uint32 a = __float_as_uint(lo);
  uint32 b = __float_as_uint(hi);
  a = (a + 0x7FFFu + ((a >> 16) & 1u)) >> 16;
  b = (b + 0x7FFFu + ((b >> 16) & 1u)) & 0xFFFF0000u;
  return a | b;
}
__device__ __forceinline__ unsigned short bf16_1(float v) {
  uint32 a = __float_as_uint(v);
  return (unsigned short)((a + 0x7FFFu + ((a >> 16) & 1u)) >> 16);
}
__device__ __forceinline__ float2 unpack_bf16(uint32 u) {
  return make_float2(__uint_as_float(u << 16), __uint_as_float(u & 0xFFFF0000u));
}
__device__ __forceinline__ short8v as_s8(uint4 u) {
  union { uint4 a; short8v b; } c; c.a = u; return c.b;
}

// Wt layout per layer: 144 cols x 128 k (bf16). Cols 0..127 = W^T; cols
// 128..135 = fused alpha vectors ws_0..3, wd_0..3; cols 136..143 = zero.
#define WT_STRIDE 18432  // 144*128

// ---------------- utility ----------------
__global__ __launch_bounds__(256) void zero_kernel(int* __restrict__ p, int n) {
  int i = blockIdx.x * 256 + threadIdx.x;
  int stride = gridDim.x * 256;
  for (; i < n; i += stride) p[i] = 0;
}

__global__ __launch_bounds__(256) void zero2_kernel(int* __restrict__ p1, int n1, int* __restrict__ p2, int n2) {
  int i0 = blockIdx.x * 256 + threadIdx.x;
  int stride = gridDim.x * 256;
  for (int i = i0; i < n1; i += stride) p1[i] = 0;
  for (int i = i0; i < n2; i += stride) p2[i] = 0;
}

// ---------------- CSR build ----------------
__global__ __launch_bounds__(256) void hist_kernel(const int* __restrict__ dst, int* __restrict__ cnt, int E, int n) {
  int e = blockIdx.x * 256 + threadIdx.x;
  if (e < E) {
    int d = clampi(dst[e], 0, n - 1);
    atomicAdd(&cnt[d], 1);
  }
}

__global__ __launch_bounds__(256) void scan_pass1(const int* __restrict__ cnt, int* __restrict__ blocksum, int n) {
  __shared__ int red[256];
  int t = threadIdx.x;
  int i = blockIdx.x * 256 + t;
  red[t] = i < n ? cnt[i] : 0;
  __syncthreads();
  for (int off = 128; off >= 1; off >>= 1) {
    if (t < off) red[t] += red[t + off];
    __syncthreads();
  }
  if (t == 0) blocksum[blockIdx.x] = red[0];
}

__global__ __launch_bounds__(256) void scan_pass2(const int* __restrict__ blocksum, int* __restrict__ blockpre,
                                                  int* __restrict__ row_start, int NB, int n) {
  __shared__ int part[256];
  int t = threadIdx.x;
  int chunk = (NB + 255) >> 8;
  int lo = t * chunk; if (lo > NB) lo = NB;
  int hi = lo + chunk; if (hi > NB) hi = NB;
  int s = 0;
  for (int i = lo; i < hi; ++i) s += blocksum[i];
  part[t] = s;
  __syncthreads();
  for (int off = 1; off < 256; off <<= 1) {
    int v = (t >= off) ? part[t - off] : 0;
    __syncthreads();
    part[t] += v;
    __syncthreads();
  }
  int run = part[t] - s;
  for (int i = lo; i < hi; ++i) {
    blockpre[i] = run;
    run += blocksum[i];
  }
  if (t == 255) row_start[n] = part[255];
}

__global__ __launch_bounds__(256) void scan_pass3(const int* __restrict__ cnt, const int* __restrict__ blockpre,
                                                  int* __restrict__ row_start, int* __restrict__ cursor, int n) {
  __shared__ int part[256];
  int t = threadIdx.x;
  int i = blockIdx.x * 256 + t;
  int c = i < n ? cnt[i] : 0;
  part[t] = c;
  __syncthreads();
  for (int off = 1; off < 256; off <<= 1) {
    int v = (t >= off) ? part[t - off] : 0;
    __syncthreads();
    part[t] += v;
    __syncthreads();
  }
  int excl = part[t] - c;
  if (i < n) {
    int b = blockpre[blockIdx.x] + excl;
    row_start[i] = b;
    cursor[i] = b;
  }
}

__global__ __launch_bounds__(256) void scatter_kernel(const int* __restrict__ src, const int* __restrict__ dst,
                                                      int* __restrict__ cursor, int* __restrict__ csr, int E, int n) {
  int e = blockIdx.x * 256 + threadIdx.x;
  if (e < E) {
    int d = clampi(dst[e], 0, n - 1);
    int s = clampi(src[e], 0, n - 1);
    int p = atomicAdd(&cursor[d], 1);
    if (p >= 0 && p < E) csr[p] = s;
  }
}

// ---------------- fused prep: xprep + W transpose + fused-alpha columns ----------
// id < n64                : pack x fp32 -> bf16 pairs
// next 3*16384 ids        : Wt[l][nc][k] = bf16(W_l[k][nc])
// next 3*2048 ids         : extra tile col8<8: ws/wd dot; col8>=8: zero
__global__ __launch_bounds__(256) void prep_kernel(const float* __restrict__ x, const float* __restrict__ W0,
                                                   const float* __restrict__ W1, const float* __restrict__ W2,
                                                   const float* __restrict__ as0, const float* __restrict__ as1,
                                                   const float* __restrict__ as2, const float* __restrict__ ad0,
                                                   const float* __restrict__ ad1, const float* __restrict__ ad2,
                                                   uint32* __restrict__ X16, unsigned short* __restrict__ wt,
                                                   long long n64) {
  long long id = (long long)blockIdx.x * 256 + threadIdx.x;
  if (id < n64) {
    float2 v = *(const float2*)&x[id * 2];
    X16[id] = pack_bf16(v.x, v.y);
    return;
  }
  int id2 = (int)(id - n64);
  if (id2 < 3 * 16384) {
    int l = id2 >> 14;
    int r = id2 & 16383;      // r = k*128 + nc (coalesced W read)
    int k = r >> 7, nc = r & 127;
    const float* W = l == 0 ? W0 : (l == 1 ? W1 : W2);
    wt[(size_t)l * WT_STRIDE + nc * 128 + k] = bf16_1(W[r]);
    return;
  }
  id2 -= 3 * 16384;
  if (id2 < 3 * 2048) {
    int l = id2 >> 11;
    int r = id2 & 2047;       // r = col8*128 + k
    int col8 = r >> 7, k = r & 127;
    const float* W = l == 0 ? W0 : (l == 1 ? W1 : W2);
    unsigned short outv = 0;
    if (col8 < 8) {
      int h = col8 & 3;
      const float* av = (col8 < 4) ? (l == 0 ? as0 : (l == 1 ? as1 : as2))
                                   : (l == 0 ? ad0 : (l == 1 ? ad1 : ad2));
      float s = 0.f;
      for (int c = 0; c < 32; ++c) s += W[k * 128 + 32 * h + c] * av[32 * h + c];
      outv = bf16_1(s);
    }
    wt[(size_t)l * WT_STRIDE + (128 + col8) * 128 + k] = outv;
  }
}

// ---------------- MFMA GEMM: H = X @ W, As/Ad via fused 9th B-tile --------------
// D layout (verified m89): col = lane&15, row = 4*(lane>>4)+reg.
// acc[8] cols 0..3 = As heads, cols 4..7 = Ad heads.
__global__ __launch_bounds__(256) void gemm_mfma(const uint32* __restrict__ X16, const unsigned short* __restrict__ Wt,
                                                 uint32* __restrict__ H16, float* __restrict__ As,
                                                 float* __restrict__ Ad, int n) {
  int t = threadIdx.x;
  int wave = t >> 6, lane = t & 63;
  int l15 = lane & 15, lg = lane >> 4;
  int row0 = blockIdx.x * 64 + wave * 16;
  int arow = row0 + l15;
  if (arow >= n) arow = n - 1;
  const uint4* xr = (const uint4*)(X16 + (size_t)arow * 64);
  uint4 a[4];
#pragma unroll
  for (int kc = 0; kc < 4; ++kc) a[kc] = xr[kc * 4 + lg];
  f32x4 acc[9];
#pragma unroll
  for (int nb = 0; nb < 9; ++nb) acc[nb] = (f32x4){0.f, 0.f, 0.f, 0.f};
#pragma unroll
  for (int kc = 0; kc < 4; ++kc) {
    uint4 b[9];
#pragma unroll
    for (int nb = 0; nb < 9; ++nb) {
      int ncol = nb * 16 + l15;
      b[nb] = *(const uint4*)(Wt + (size_t)ncol * 128 + kc * 32 + lg * 8);
    }
#pragma unroll
    for (int nb = 0; nb < 9; ++nb)
      acc[nb] = __builtin_amdgcn_mfma_f32_16x16x32_bf16(as_s8(a[kc]), as_s8(b[nb]), acc[nb], 0, 0, 0);
  }
#pragma unroll
  for (int r = 0; r < 4; ++r) {
    int gr = row0 + lg * 4 + r;
    bool ok = gr < n;
#pragma unroll
    for (int nb = 0; nb < 8; ++nb) {
      float mine = acc[nb][r];
      float other = __shfl_xor(mine, 1);
      if (ok && (lane & 1) == 0) H16[(size_t)gr * 64 + nb * 8 + (l15 >> 1)] = pack_bf16(mine, other);
    }
    float av = acc[8][r];
    if (ok && l15 < 4) As[gr * 4 + l15] = av;
    if (ok && l15 >= 4 && l15 < 8) Ad[gr * 4 + (l15 - 4)] = av;
  }
}

// ---------------- fused softmax + aggregation (wave per node, 8-deep MLP) --------
template <bool OUTFP32>
__global__ __launch_bounds__(256) void agg_kernel(const uint32* __restrict__ H16, const float* __restrict__ As,
                                                  const float* __restrict__ Ad, const int* __restrict__ row_start,
                                                  const int* __restrict__ csr, const float* __restrict__ bias,
                                                  void* __restrict__ outv, int n) {
  int wid = (blockIdx.x * 256 + threadIdx.x) >> 6;
  int lane = threadIdx.x & 63;
  if (wid >= n) return;
  int base = row_start[wid];
  int deg = row_start[wid + 1] - base;
  if (deg < 0) deg = 0;
  int hsel = lane >> 4;
  float adsel = Ad[wid * 4 + hsel];
  float pself = __expf(leaky(As[wid * 4 + hsel] + adsel));
  float2 hv = unpack_bf16(H16[(size_t)wid * 64 + lane]);
  float den = pself;
  float acc0 = pself * hv.x, acc1 = pself * hv.y;
  for (int chunk = 0; chunk < deg; chunk += 64) {
    int j = chunk + lane;
    int smine = (j < deg) ? clampi(csr[base + j], 0, n - 1) : 0;
    int cnt_ = deg - chunk; if (cnt_ > 64) cnt_ = 64;
    float pm[4];
#pragma unroll
    for (int k = 0; k < 4; ++k) {
      pm[k] = 0.f;
      if (k * 16 < cnt_) {  // wave-uniform: skip whole alpha group
        int slot = k * 16 + (lane & 15);
        int sk = __shfl(smine, slot);
        float e = As[sk * 4 + hsel];
        pm[k] = (slot < cnt_) ? __expf(leaky(e + adsel)) : 0.f;
      }
    }
#pragma unroll
    for (int k = 0; k < 4; ++k) {
      if (k * 16 >= cnt_) break;
#pragma unroll
      for (int b = 0; b < 2; ++b) {
        int u0 = k * 16 + b * 8;
        if (u0 >= cnt_) break;
        int ss[8];
        float aw[8];
        float2 h2[8];
#pragma unroll
        for (int i = 0; i < 8; ++i) {
          int u = u0 + i;
          int sv = __shfl(smine, u);
          float av = __shfl(pm[k], (lane & 48) + (u & 15));
          ss[i] = (u < cnt_) ? sv : 0;
          aw[i] = (u < cnt_) ? av : 0.f;
        }
#pragma unroll
        for (int i = 0; i < 8; ++i) h2[i] = unpack_bf16(H16[(size_t)((uint32)ss[i] * 64 + lane)]);
#pragma unroll
        for (int i = 0; i < 8; ++i) {
          den += aw[i];
          acc0 += aw[i] * h2[i].x;
          acc1 += aw[i] * h2[i].y;
        }
      }
    }
  }
  float inv = 1.f / den;
  float2 bv = *(const float2*)&bias[2 * lane];
  float r0v = fmaxf(acc0 * inv + bv.x, 0.f);
  float r1v = fmaxf(acc1 * inv + bv.y, 0.f);
  if constexpr (OUTFP32) {
    ((float2*)outv)[(size_t)wid * 64 + lane] = make_float2(r0v, r1v);
  } else {
    ((uint32*)outv)[(size_t)wid * 64 + lane] = pack_bf16(r0v, r1v);
  }
}

// ---------------- pooling ----------------
__global__ __launch_bounds__(128) void pool_kernel(const float* __restrict__ X, const int* __restrict__ batch,
                                                   float* __restrict__ pooled, int n, int G) {
  int c = threadIdx.x;
  int n0 = blockIdx.x * 64;
  if (n0 >= n) return;
  int end = n0 + 64 < n ? n0 + 64 : n;
  int curg = clampi(batch[n0], 0, G - 1);
  float acc = 0.f;
  for (int i = n0; i < end; ++i) {
    int g = clampi(batch[i], 0, G - 1);
    if (g != curg) {
      atomicAdd(&pooled[curg * 128 + c], acc);
      acc = 0.f;
      curg = g;
    }
    acc += X[(size_t)i * 128 + c];
  }
  atomicAdd(&pooled[curg * 128 + c], acc);
}

__global__ __launch_bounds__(64) void logits_kernel(const float* __restrict__ pooled, const float* __restrict__ Wh,
                                                    const float* __restrict__ bh, float* __restrict__ out) {
  int g = blockIdx.x, lane = threadIdx.x;
  float p0 = pooled[g * 128 + lane];
  float p1 = pooled[g * 128 + lane + 64];
  for (int o = 0; o < 10; ++o) {
    float v = p0 * Wh[lane * 10 + o] + p1 * Wh[(lane + 64) * 10 + o];
#pragma unroll
    for (int off = 32; off >= 1; off >>= 1) v += __shfl_xor(v, off);
    if (lane == 0) out[g * 10 + o] = v + bh[o];
  }
}

extern "C" void kernel_launch(void* const* d_in, const int* in_sizes, int n_in,
                              void* d_out, int out_size, void* d_ws, size_t ws_size,
                              hipStream_t stream) {
  const float *x, *Wl[3], *asr[3], *adr[3], *bias[3], *Wh, *bh;
  const int *edge_index, *batch;
  long long E_ll;
  if (n_in >= 17) {
    x = (const float*)d_in[0];
    for (int l = 0; l < 3; ++l) {
      Wl[l] = (const float*)d_in[1 + l];
      asr[l] = (const float*)d_in[4 + l];
      adr[l] = (const float*)d_in[7 + l];
      bias[l] = (const float*)d_in[10 + l];
    }
    Wh = (const float*)d_in[13];
    bh = (const float*)d_in[14];
    edge_index = (const int*)d_in[15];
    batch = (const int*)d_in[16];
    E_ll = (long long)in_sizes[15] / 2;
  } else if (n_in >= 9) {
    x = (const float*)d_in[0];
    const float* Wc = (const float*)d_in[1];
    const float* ac = (const float*)d_in[2];
    const float* dc = (const float*)d_in[3];
    const float* bc = (const float*)d_in[4];
    for (int l = 0; l < 3; ++l) {
      Wl[l] = Wc + (size_t)l * HC * HC;
      asr[l] = ac + (size_t)l * HC;
      adr[l] = dc + (size_t)l * HC;
      bias[l] = bc + (size_t)l * HC;
    }
    Wh = (const float*)d_in[5];
    bh = (const float*)d_in[6];
    edge_index = (const int*)d_in[7];
    batch = (const int*)d_in[8];
    E_ll = (long long)in_sizes[7] / 2;
  } else {
    zero_kernel<<<(out_size + 255) / 256, 256, 0, stream>>>((int*)d_out, out_size);
    return;
  }
  int N = in_sizes[0] / HC;
  int G = out_size / 10;
  if (N <= 0 || G <= 0 || E_ll <= 0 || E_ll > (1LL << 30)) {
    zero_kernel<<<(out_size + 255) / 256, 256, 0, stream>>>((int*)d_out, out_size);
    return;
  }
  int E = (int)E_ll;
  int NB = (N + 255) / 256;

  char* w = (char*)d_ws;
  size_t off = 0;
  auto take = [&](size_t bytes) -> char* {
    char* p = w + off;
    off = (off + bytes + 511) & ~(size_t)511;
    return p;
  };
  uint32* H16 = (uint32*)take((size_t)N * 64 * 4);
  uint32* X16 = (uint32*)take((size_t)N * 64 * 4);
  float* bufQ = (float*)take((size_t)N * HC * 4);   // layer-2 fp32 output
  uint32* Xa = (uint32*)bufQ;                        // aliased: bf16 x (consumed before bufQ written)
  float* As = (float*)take((size_t)N * NHEAD * 4);
  float* Ad = (float*)take((size_t)N * NHEAD * 4);
  int* cnt = (int*)take((size_t)N * 4);
  int* row_start = (int*)take((size_t)(N + 1) * 4);
  int* cursor = (int*)take((size_t)N * 4);
  int* csr = (int*)take((size_t)E * 4);
  int* blocksum = (int*)take((size_t)NB * 4);
  int* blockpre = (int*)take((size_t)NB * 4);
  float* pooled = (float*)take((size_t)G * HC * 4);
  unsigned short* wt16 = (unsigned short*)take((size_t)3 * WT_STRIDE * 2);

  if (off > ws_size) {
    zero_kernel<<<(out_size + 255) / 256, 256, 0, stream>>>((int*)d_out, out_size);
    return;
  }

  const int* esrc = edge_index;
  const int* edst = edge_index + E;

  long long n64 = (long long)N * 64;
  long long prep_items = n64 + 3 * 16384 + 3 * 2048;
  prep_kernel<<<(int)((prep_items + 255) / 256), 256, 0, stream>>>(
      x, Wl[0], Wl[1], Wl[2], asr[0], asr[1], asr[2], adr[0], adr[1], adr[2], Xa, wt16, n64);

  int zgrid = (N > G * HC ? N : G * HC);
  zero2_kernel<<<(zgrid + 255) / 256, 256, 0, stream>>>(cnt, N, (int*)pooled, G * HC);
  hist_kernel<<<(E + 255) / 256, 256, 0, stream>>>(edst, cnt, E, N);
  scan_pass1<<<NB, 256, 0, stream>>>(cnt, blocksum, N);
  scan_pass2<<<1, 256, 0, stream>>>(blocksum, blockpre, row_start, NB, N);
  scan_pass3<<<NB, 256, 0, stream>>>(cnt, blockpre, row_start, cursor, N);
  scatter_kernel<<<(E + 255) / 256, 256, 0, stream>>>(esrc, edst, cursor, csr, E, N);

  int gemm_grid = (N + 63) / 64;
  int agg_grid = (N + 3) / 4;

  // layer 0
  gemm_mfma<<<gemm_grid, 256, 0, stream>>>(Xa, wt16, H16, As, Ad, N);
  agg_kernel<false><<<agg_grid, 256, 0, stream>>>(H16, As, Ad, row_start, csr, bias[0], X16, N);
  // layer 1
  gemm_mfma<<<gemm_grid, 256, 0, stream>>>(X16, wt16 + WT_STRIDE, H16, As, Ad, N);
  agg_kernel<false><<<agg_grid, 256, 0, stream>>>(H16, As, Ad, row_start, csr, bias[1], X16, N);
  // layer 2 (agg -> fp32 bufQ; Xa no longer needed)
  gemm_mfma<<<gemm_grid, 256, 0, stream>>>(X16, wt16 + 2 * WT_STRIDE, H16, As, Ad, N);
  agg_kernel<true><<<agg_grid, 256, 0, stream>>>(H16, As, Ad, row_start, csr, bias[2], bufQ, N);

  pool_kernel<<<(N + 63) / 64, 128, 0, stream>>>(bufQ, batch, pooled, N, G);
  logits_kernel<<<G, 64, 0, stream>>>(pooled, Wh, bh, (float*)d_out);
}

// Round 13
// 327.486 us; speedup vs baseline: 1.2601x; 1.0184x over previous
//
#include <hip/hip_runtime.h>
#include <hip/hip_bf16.h>

#define HC 128
#define NHEAD 4
#define NEG 0.2f
#define CPAD 16  // ints per counter line (64 B) to kill atomic false sharing

typedef unsigned int uint32;
typedef __attribute__((ext_vector_type(8))) short short8v;   // 8 bf16 = 4 VGPR
typedef __attribute__((ext_vector_type(4))) float f32x4;

__device__ __forceinline__ float leaky(float v) { return v > 0.f ? v : NEG * v; }
__device__ __forceinline__ int clampi(int v, int lo, int hi) { return v < lo ? lo : (v > hi ? hi : v); }

__device__ __forceinline__ uint32 pack_bf16(float lo, float hi) {
  uint32 a = __float_as_uint(lo);
  uint32 b = __float_as_uint(hi);
  a = (a + 0x7FFFu + ((a >> 16) & 1u)) >> 16;
  b = (b + 0x7FFFu + ((b >> 16) & 1u)) & 0xFFFF0000u;
  return a | b;
}
__device__ __forceinline__ unsigned short bf16_1(float v) {
  uint32 a = __float_as_uint(v);
  return (unsigned short)((a + 0x7FFFu + ((a >> 16) & 1u)) >> 16);
}
__device__ __forceinline__ float2 unpack_bf16(uint32 u) {
  return make_float2(__uint_as_float(u << 16), __uint_as_float(u & 0xFFFF0000u));
}
__device__ __forceinline__ short8v as_s8(uint4 u) {
  union { uint4 a; short8v b; } c; c.a = u; return c.b;
}

// Wt layout per layer: 144 cols x 128 k (bf16). Cols 0..127 = W^T; cols
// 128..135 = fused alpha vectors ws_0..3, wd_0..3; cols 136..143 = zero.
#define WT_STRIDE 18432  // 144*128

// ---------------- utility ----------------
__global__ __launch_bounds__(256) void zero_kernel(int* __restrict__ p, int n) {
  int i = blockIdx.x * 256 + threadIdx.x;
  int stride = gridDim.x * 256;
  for (; i < n; i += stride) p[i] = 0;
}

// ---------------- CSR build ----------------
__global__ __launch_bounds__(256) void hist_kernel(const int* __restrict__ dst, int* __restrict__ cnt, int E, int n) {
  int e = blockIdx.x * 256 + threadIdx.x;
  if (e < E) {
    int d = clampi(dst[e], 0, n - 1);
    atomicAdd(&cnt[d * CPAD], 1);
  }
}

__global__ __launch_bounds__(256) void scan_pass1(const int* __restrict__ cnt, int* __restrict__ blocksum, int n) {
  __shared__ int red[256];
  int t = threadIdx.x;
  int i = blockIdx.x * 256 + t;
  red[t] = i < n ? cnt[i * CPAD] : 0;
  __syncthreads();
  for (int off = 128; off >= 1; off >>= 1) {
    if (t < off) red[t] += red[t + off];
    __syncthreads();
  }
  if (t == 0) blocksum[blockIdx.x] = red[0];
}

__global__ __launch_bounds__(256) void scan_pass2(const int* __restrict__ blocksum, int* __restrict__ blockpre,
                                                  int* __restrict__ row_start, int NB, int n) {
  __shared__ int part[256];
  int t = threadIdx.x;
  int chunk = (NB + 255) >> 8;
  int lo = t * chunk; if (lo > NB) lo = NB;
  int hi = lo + chunk; if (hi > NB) hi = NB;
  int s = 0;
  for (int i = lo; i < hi; ++i) s += blocksum[i];
  part[t] = s;
  __syncthreads();
  for (int off = 1; off < 256; off <<= 1) {
    int v = (t >= off) ? part[t - off] : 0;
    __syncthreads();
    part[t] += v;
    __syncthreads();
  }
  int run = part[t] - s;
  for (int i = lo; i < hi; ++i) {
    blockpre[i] = run;
    run += blocksum[i];
  }
  if (t == 255) row_start[n] = part[255];
}

__global__ __launch_bounds__(256) void scan_pass3(const int* __restrict__ cnt, const int* __restrict__ blockpre,
                                                  int* __restrict__ row_start, int* __restrict__ cursor, int n) {
  __shared__ int part[256];
  int t = threadIdx.x;
  int i = blockIdx.x * 256 + t;
  int c = i < n ? cnt[i * CPAD] : 0;
  part[t] = c;
  __syncthreads();
  for (int off = 1; off < 256; off <<= 1) {
    int v = (t >= off) ? part[t - off] : 0;
    __syncthreads();
    part[t] += v;
    __syncthreads();
  }
  int excl = part[t] - c;
  if (i < n) {
    int b = blockpre[blockIdx.x] + excl;
    row_start[i] = b;
    cursor[i * CPAD] = b;
  }
}

__global__ __launch_bounds__(256) void scatter_kernel(const int* __restrict__ src, const int* __restrict__ dst,
                                                      int* __restrict__ cursor, int* __restrict__ csr, int E, int n) {
  int e = blockIdx.x * 256 + threadIdx.x;
  if (e < E) {
    int d = clampi(dst[e], 0, n - 1);
    int s = clampi(src[e], 0, n - 1);
    int p = atomicAdd(&cursor[d * CPAD], 1);
    if (p >= 0 && p < E) csr[p] = s;
  }
}

// ---------------- fused prep: xprep + W transpose + fused-alpha cols + zero-init --
// id ranges (in order): [0,n64) x-pack; [+3*16384) Wt; [+3*2048) alpha cols;
// [+N*CPAD) zero cnt; [+G*128) zero pooled.
__global__ __launch_bounds__(256) void prep_kernel(const float* __restrict__ x, const float* __restrict__ W0,
                                                   const float* __restrict__ W1, const float* __restrict__ W2,
                                                   const float* __restrict__ as0, const float* __restrict__ as1,
                                                   const float* __restrict__ as2, const float* __restrict__ ad0,
                                                   const float* __restrict__ ad1, const float* __restrict__ ad2,
                                                   uint32* __restrict__ X16, unsigned short* __restrict__ wt,
                                                   int* __restrict__ cnt, float* __restrict__ pooled,
                                                   long long n64, int N, int Gp) {
  long long id = (long long)blockIdx.x * 256 + threadIdx.x;
  if (id < n64) {
    float2 v = *(const float2*)&x[id * 2];
    X16[id] = pack_bf16(v.x, v.y);
    return;
  }
  long long id2l = id - n64;
  if (id2l < 3 * 16384) {
    int id2 = (int)id2l;
    int l = id2 >> 14;
    int r = id2 & 16383;      // r = k*128 + nc (coalesced W read)
    int k = r >> 7, nc = r & 127;
    const float* W = l == 0 ? W0 : (l == 1 ? W1 : W2);
    wt[(size_t)l * WT_STRIDE + nc * 128 + k] = bf16_1(W[r]);
    return;
  }
  id2l -= 3 * 16384;
  if (id2l < 3 * 2048) {
    int id2 = (int)id2l;
    int l = id2 >> 11;
    int r = id2 & 2047;       // r = col8*128 + k
    int col8 = r >> 7, k = r & 127;
    const float* W = l == 0 ? W0 : (l == 1 ? W1 : W2);
    unsigned short outv = 0;
    if (col8 < 8) {
      int h = col8 & 3;
      const float* av = (col8 < 4) ? (l == 0 ? as0 : (l == 1 ? as1 : as2))
                                   : (l == 0 ? ad0 : (l == 1 ? ad1 : ad2));
      float s = 0.f;
      for (int c = 0; c < 32; ++c) s += W[k * 128 + 32 * h + c] * av[32 * h + c];
      outv = bf16_1(s);
    }
    wt[(size_t)l * WT_STRIDE + (128 + col8) * 128 + k] = outv;
    return;
  }
  id2l -= 3 * 2048;
  if (id2l < (long long)N * CPAD) {
    cnt[id2l] = 0;
    return;
  }
  id2l -= (long long)N * CPAD;
  if (id2l < (long long)Gp * 128) pooled[id2l] = 0.f;
}

// ---------------- MFMA GEMM: H = X @ W, As/Ad via fused 9th B-tile --------------
// D layout (verified m89): col = lane&15, row = 4*(lane>>4)+reg.
__global__ __launch_bounds__(256) void gemm_mfma(const uint32* __restrict__ X16, const unsigned short* __restrict__ Wt,
                                                 uint32* __restrict__ H16, float* __restrict__ As,
                                                 float* __restrict__ Ad, int n) {
  int t = threadIdx.x;
  int wave = t >> 6, lane = t & 63;
  int l15 = lane & 15, lg = lane >> 4;
  int row0 = blockIdx.x * 64 + wave * 16;
  int arow = row0 + l15;
  if (arow >= n) arow = n - 1;
  const uint4* xr = (const uint4*)(X16 + (size_t)arow * 64);
  uint4 a[4];
#pragma unroll
  for (int kc = 0; kc < 4; ++kc) a[kc] = xr[kc * 4 + lg];
  f32x4 acc[9];
#pragma unroll
  for (int nb = 0; nb < 9; ++nb) acc[nb] = (f32x4){0.f, 0.f, 0.f, 0.f};
#pragma unroll
  for (int kc = 0; kc < 4; ++kc) {
    uint4 b[9];
#pragma unroll
    for (int nb = 0; nb < 9; ++nb) {
      int ncol = nb * 16 + l15;
      b[nb] = *(const uint4*)(Wt + (size_t)ncol * 128 + kc * 32 + lg * 8);
    }
#pragma unroll
    for (int nb = 0; nb < 9; ++nb)
      acc[nb] = __builtin_amdgcn_mfma_f32_16x16x32_bf16(as_s8(a[kc]), as_s8(b[nb]), acc[nb], 0, 0, 0);
  }
#pragma unroll
  for (int r = 0; r < 4; ++r) {
    int gr = row0 + lg * 4 + r;
    bool ok = gr < n;
#pragma unroll
    for (int nb = 0; nb < 8; ++nb) {
      float mine = acc[nb][r];
      float other = __shfl_xor(mine, 1);
      if (ok && (lane & 1) == 0) H16[(size_t)gr * 64 + nb * 8 + (l15 >> 1)] = pack_bf16(mine, other);
    }
    float av = acc[8][r];
    if (ok && l15 < 4) As[gr * 4 + l15] = av;
    if (ok && l15 >= 4 && l15 < 8) Ad[gr * 4 + (l15 - 4)] = av;
  }
}

// ---------------- fused softmax + aggregation (wave per node, 8-deep MLP) --------
template <bool OUTFP32>
__global__ __launch_bounds__(256) void agg_kernel(const uint32* __restrict__ H16, const float* __restrict__ As,
                                                  const float* __restrict__ Ad, const int* __restrict__ row_start,
                                                  const int* __restrict__ csr, const float* __restrict__ bias,
                                                  void* __restrict__ outv, int n) {
  int wid = (blockIdx.x * 256 + threadIdx.x) >> 6;
  int lane = threadIdx.x & 63;
  if (wid >= n) return;
  int base = row_start[wid];
  int deg = row_start[wid + 1] - base;
  if (deg < 0) deg = 0;
  int hsel = lane >> 4;
  float adsel = Ad[wid * 4 + hsel];
  float pself = __expf(leaky(As[wid * 4 + hsel] + adsel));
  float2 hv = unpack_bf16(H16[(size_t)wid * 64 + lane]);
  float den = pself;
  float acc0 = pself * hv.x, acc1 = pself * hv.y;
  for (int chunk = 0; chunk < deg; chunk += 64) {
    int j = chunk + lane;
    int smine = (j < deg) ? clampi(csr[base + j], 0, n - 1) : 0;
    int cnt_ = deg - chunk; if (cnt_ > 64) cnt_ = 64;
    float pm[4];
#pragma unroll
    for (int k = 0; k < 4; ++k) {
      pm[k] = 0.f;
      if (k * 16 < cnt_) {
        int slot = k * 16 + (lane & 15);
        int sk = __shfl(smine, slot);
        float e = As[sk * 4 + hsel];
        pm[k] = (slot < cnt_) ? __expf(leaky(e + adsel)) : 0.f;
      }
    }
#pragma unroll
    for (int k = 0; k < 4; ++k) {
      if (k * 16 >= cnt_) break;
#pragma unroll
      for (int b = 0; b < 2; ++b) {
        int u0 = k * 16 + b * 8;
        if (u0 >= cnt_) break;
        int ss[8];
        float aw[8];
        float2 h2[8];
#pragma unroll
        for (int i = 0; i < 8; ++i) {
          int u = u0 + i;
          int sv = __shfl(smine, u);
          float av = __shfl(pm[k], (lane & 48) + (u & 15));
          ss[i] = (u < cnt_) ? sv : 0;
          aw[i] = (u < cnt_) ? av : 0.f;
        }
#pragma unroll
        for (int i = 0; i < 8; ++i) h2[i] = unpack_bf16(H16[(size_t)((uint32)ss[i] * 64 + lane)]);
#pragma unroll
        for (int i = 0; i < 8; ++i) {
          den += aw[i];
          acc0 += aw[i] * h2[i].x;
          acc1 += aw[i] * h2[i].y;
        }
      }
    }
  }
  float inv = 1.f / den;
  float2 bv = *(const float2*)&bias[2 * lane];
  float r0v = fmaxf(acc0 * inv + bv.x, 0.f);
  float r1v = fmaxf(acc1 * inv + bv.y, 0.f);
  if constexpr (OUTFP32) {
    ((float2*)outv)[(size_t)wid * 64 + lane] = make_float2(r0v, r1v);
  } else {
    ((uint32*)outv)[(size_t)wid * 64 + lane] = pack_bf16(r0v, r1v);
  }
}

// ---------------- pooling ----------------
__global__ __launch_bounds__(128) void pool_kernel(const float* __restrict__ X, const int* __restrict__ batch,
                                                   float* __restrict__ pooled, int n, int G) {
  int c = threadIdx.x;
  int n0 = blockIdx.x * 64;
  if (n0 >= n) return;
  int end = n0 + 64 < n ? n0 + 64 : n;
  int curg = clampi(batch[n0], 0, G - 1);
  float acc = 0.f;
  for (int i = n0; i < end; ++i) {
    int g = clampi(batch[i], 0, G - 1);
    if (g != curg) {
      atomicAdd(&pooled[curg * 128 + c], acc);
      acc = 0.f;
      curg = g;
    }
    acc += X[(size_t)i * 128 + c];
  }
  atomicAdd(&pooled[curg * 128 + c], acc);
}

__global__ __launch_bounds__(64) void logits_kernel(const float* __restrict__ pooled, const float* __restrict__ Wh,
                                                    const float* __restrict__ bh, float* __restrict__ out) {
  int g = blockIdx.x, lane = threadIdx.x;
  float p0 = pooled[g * 128 + lane];
  float p1 = pooled[g * 128 + lane + 64];
  for (int o = 0; o < 10; ++o) {
    float v = p0 * Wh[lane * 10 + o] + p1 * Wh[(lane + 64) * 10 + o];
#pragma unroll
    for (int off = 32; off >= 1; off >>= 1) v += __shfl_xor(v, off);
    if (lane == 0) out[g * 10 + o] = v + bh[o];
  }
}

extern "C" void kernel_launch(void* const* d_in, const int* in_sizes, int n_in,
                              void* d_out, int out_size, void* d_ws, size_t ws_size,
                              hipStream_t stream) {
  const float *x, *Wl[3], *asr[3], *adr[3], *bias[3], *Wh, *bh;
  const int *edge_index, *batch;
  long long E_ll;
  if (n_in >= 17) {
    x = (const float*)d_in[0];
    for (int l = 0; l < 3; ++l) {
      Wl[l] = (const float*)d_in[1 + l];
      asr[l] = (const float*)d_in[4 + l];
      adr[l] = (const float*)d_in[7 + l];
      bias[l] = (const float*)d_in[10 + l];
    }
    Wh = (const float*)d_in[13];
    bh = (const float*)d_in[14];
    edge_index = (const int*)d_in[15];
    batch = (const int*)d_in[16];
    E_ll = (long long)in_sizes[15] / 2;
  } else if (n_in >= 9) {
    x = (const float*)d_in[0];
    const float* Wc = (const float*)d_in[1];
    const float* ac = (const float*)d_in[2];
    const float* dc = (const float*)d_in[3];
    const float* bc = (const float*)d_in[4];
    for (int l = 0; l < 3; ++l) {
      Wl[l] = Wc + (size_t)l * HC * HC;
      asr[l] = ac + (size_t)l * HC;
      adr[l] = dc + (size_t)l * HC;
      bias[l] = bc + (size_t)l * HC;
    }
    Wh = (const float*)d_in[5];
    bh = (const float*)d_in[6];
    edge_index = (const int*)d_in[7];
    batch = (const int*)d_in[8];
    E_ll = (long long)in_sizes[7] / 2;
  } else {
    zero_kernel<<<(out_size + 255) / 256, 256, 0, stream>>>((int*)d_out, out_size);
    return;
  }
  int N = in_sizes[0] / HC;
  int G = out_size / 10;
  if (N <= 0 || G <= 0 || E_ll <= 0 || E_ll > (1LL << 30)) {
    zero_kernel<<<(out_size + 255) / 256, 256, 0, stream>>>((int*)d_out, out_size);
    return;
  }
  int E = (int)E_ll;
  int NB = (N + 255) / 256;

  char* w = (char*)d_ws;
  size_t off = 0;
  auto take = [&](size_t bytes) -> char* {
    char* p = w + off;
    off = (off + bytes + 511) & ~(size_t)511;
    return p;
  };
  uint32* H16 = (uint32*)take((size_t)N * 64 * 4);
  uint32* X16 = (uint32*)take((size_t)N * 64 * 4);
  float* bufQ = (float*)take((size_t)N * HC * 4);   // layer-2 fp32 output
  uint32* Xa = (uint32*)bufQ;                        // aliased: bf16 x (consumed before bufQ written)
  float* As = (float*)take((size_t)N * NHEAD * 4);
  float* Ad = (float*)take((size_t)N * NHEAD * 4);
  int* cnt = (int*)take((size_t)N * CPAD * 4);
  int* row_start = (int*)take((size_t)(N + 1) * 4);
  int* cursor = (int*)take((size_t)N * CPAD * 4);
  int* csr = (int*)take((size_t)E * 4);
  int* blocksum = (int*)take((size_t)NB * 4);
  int* blockpre = (int*)take((size_t)NB * 4);
  float* pooled = (float*)take((size_t)G * HC * 4);
  unsigned short* wt16 = (unsigned short*)take((size_t)3 * WT_STRIDE * 2);

  if (off > ws_size) {
    zero_kernel<<<(out_size + 255) / 256, 256, 0, stream>>>((int*)d_out, out_size);
    return;
  }

  const int* esrc = edge_index;
  const int* edst = edge_index + E;

  long long n64 = (long long)N * 64;
  long long prep_items = n64 + 3 * 16384 + 3 * 2048 + (long long)N * CPAD + (long long)G * 128;
  prep_kernel<<<(int)((prep_items + 255) / 256), 256, 0, stream>>>(
      x, Wl[0], Wl[1], Wl[2], asr[0], asr[1], asr[2], adr[0], adr[1], adr[2], Xa, wt16, cnt, pooled, n64, N, G);

  hist_kernel<<<(E + 255) / 256, 256, 0, stream>>>(edst, cnt, E, N);
  scan_pass1<<<NB, 256, 0, stream>>>(cnt, blocksum, N);
  scan_pass2<<<1, 256, 0, stream>>>(blocksum, blockpre, row_start, NB, N);
  scan_pass3<<<NB, 256, 0, stream>>>(cnt, blockpre, row_start, cursor, N);
  scatter_kernel<<<(E + 255) / 256, 256, 0, stream>>>(esrc, edst, cursor, csr, E, N);

  int gemm_grid = (N + 63) / 64;
  int agg_grid = (N + 3) / 4;

  // layer 0
  gemm_mfma<<<gemm_grid, 256, 0, stream>>>(Xa, wt16, H16, As, Ad, N);
  agg_kernel<false><<<agg_grid, 256, 0, stream>>>(H16, As, Ad, row_start, csr, bias[0], X16, N);
  // layer 1
  gemm_mfma<<<gemm_grid, 256, 0, stream>>>(X16, wt16 + WT_STRIDE, H16, As, Ad, N);
  agg_kernel<false><<<agg_grid, 256, 0, stream>>>(H16, As, Ad, row_start, csr, bias[1], X16, N);
  // layer 2 (agg -> fp32 bufQ; Xa no longer needed)
  gemm_mfma<<<gemm_grid, 256, 0, stream>>>(X16, wt16 + 2 * WT_STRIDE, H16, As, Ad, N);
  agg_kernel<true><<<agg_grid, 256, 0, stream>>>(H16, As, Ad, row_start, csr, bias[2], bufQ, N);

  pool_kernel<<<(N + 63) / 64, 128, 0, stream>>>(bufQ, batch, pooled, N, G);
  logits_kernel<<<G, 64, 0, stream>>>(pooled, Wh, bh, (float*)d_out);
}